// Round 4
// baseline (302.879 us; speedup 1.0000x reference)
//
#include <hip/hip_runtime.h>

typedef unsigned short u16;
typedef __attribute__((ext_vector_type(8))) short v8s;   // 8 x bf16 MFMA operand
typedef __attribute__((ext_vector_type(4))) float v4f;   // MFMA accumulator

__device__ __forceinline__ u16 f2bf(float f) {
  unsigned u = __float_as_uint(f);
  u += 0x7FFF + ((u >> 16) & 1);   // RNE
  return (u16)(u >> 16);
}

// pack two floats -> {hi.bf16, lo.bf16} u32 (round-half-up, fine at this scale)
// NOTE: keep the proven perm version; v_cvt_pk_bf16_f32 asm was implicated in
// the r1/r2 absmax failures (0.4375 residual with table exonerated by r3 pass).
__device__ __forceinline__ unsigned pk2bf(float lo, float hi) {
  unsigned a = __float_as_uint(lo) + 0x8000u;
  unsigned b = __float_as_uint(hi) + 0x8000u;
  return __builtin_amdgcn_perm(b, a, 0x07060302);
}

__device__ __forceinline__ v4f zero4() {
  v4f z; z[0] = 0.f; z[1] = 0.f; z[2] = 0.f; z[3] = 0.f; return z;
}

__device__ __forceinline__ void async16(const u16* g, u16* l) {
  __builtin_amdgcn_global_load_lds(
      (const __attribute__((address_space(1))) unsigned int*)g,
      (__attribute__((address_space(3))) unsigned int*)l, 16, 0, 0);
}

// reduce x to [-pi,pi] then native sin/cos (v_sin valid range)
__device__ __forceinline__ void fast_sincos(float x, float* s, float* c) {
  float k = rintf(x * 0.15915494309189535f);
  float r = __builtin_fmaf(k, -6.28125f, x);
  r = __builtin_fmaf(k, -0.0019353071795864769f, r);
  *s = __sinf(r);
  *c = __cosf(r);
}

#define ATTN_SCL (0.125f * 1.4426950408889634f)  // 1/sqrt(64) * log2(e), folded into Q

// ---------------- fused fp32 -> bf16 cast of all three inputs ----------------
// dst slots are contiguous in ws: xb [0,16M) | wqkvb [16M,22M) | woutb [22M,24M)
// as float4 indices: x 0..2097152, w_qkv ..2883584, w_out ..3145728 (block-uniform)
__global__ __launch_bounds__(256) void cast_all_k(const float* __restrict__ x,
                                                  const float* __restrict__ wq,
                                                  const float* __restrict__ wo,
                                                  u16* __restrict__ dst) {
  int i = blockIdx.x * 256 + threadIdx.x;
  const float4* s;
  int si;
  if (i < 2097152) { s = (const float4*)x;  si = i; }
  else if (i < 2883584) { s = (const float4*)wq; si = i - 2097152; }
  else { s = (const float4*)wo; si = i - 2883584; }
  float4 v = s[si];
  ((ushort4*)dst)[i] = make_ushort4(f2bf(v.x), f2bf(v.y), f2bf(v.z), f2bf(v.w));
}

// LDS bank swizzle: 16B granule g of row r lives at slot g^(r&7).
// Staging (global_load_lds is lane-contiguous on the LDS side): lane loads
// global granule (slot ^ (row&7)) so slot s holds data granule s^(r&7).

// ---------------- 128x128 GEMM mainloop (qkv) ----------------
// C(128x128) = A[M,K] @ B[N,K]^T   (both bf16 row-major, K multiple of 64)
__device__ __forceinline__ void gemm_core(const u16* __restrict__ A,
                                          const u16* __restrict__ B, int K,
                                          int row0, int col0, u16* As, u16* Bs,
                                          v4f acc[4][4]) {
  const int tid = threadIdx.x;
  const int lane = tid & 63;
  const int wm = (tid >> 7) & 1;
  const int wn = (tid >> 6) & 1;
  const int ln = lane & 15, quad = lane >> 4;
#pragma unroll
  for (int i = 0; i < 4; ++i)
#pragma unroll
    for (int j = 0; j < 4; ++j) acc[i][j] = zero4();
  const int rA = tid >> 3;
  const int cA = (((tid & 7) ^ (rA & 7)) << 3);   // swizzled source granule
  for (int kt = 0; kt < K; kt += 64) {
#pragma unroll
    for (int i = 0; i < 4; ++i) {
      async16(A + (size_t)(row0 + i * 32 + rA) * K + kt + cA, As + i * 2048 + tid * 8);
      async16(B + (size_t)(col0 + i * 32 + rA) * K + kt + cA, Bs + i * 2048 + tid * 8);
    }
    __syncthreads();
#pragma unroll
    for (int kk = 0; kk < 2; ++kk) {
      const int go = (((kk * 4 + quad) ^ (ln & 7)) << 3);  // swizzled read granule
      v8s af[4], bfr[4];
#pragma unroll
      for (int i = 0; i < 4; ++i) {
        af[i]  = *(const v8s*)(As + (wm * 64 + i * 16 + ln) * 64 + go);
        bfr[i] = *(const v8s*)(Bs + (wn * 64 + i * 16 + ln) * 64 + go);
      }
      __builtin_amdgcn_s_setprio(1);
#pragma unroll
      for (int i = 0; i < 4; ++i)
#pragma unroll
        for (int j = 0; j < 4; ++j)
          acc[i][j] = __builtin_amdgcn_mfma_f32_16x16x32_bf16(af[i], bfr[j], acc[i][j], 0, 0, 0);
      __builtin_amdgcn_s_setprio(0);
    }
    __syncthreads();
  }
}

// ---------------- QKV GEMM + fused RoPE/reshape epilogue ----------------
// q gets the softmax scale folded in (scale commutes with rotation)
__global__ __launch_bounds__(256) void gemm_qkv_rope(const u16* __restrict__ A,
                                                     const u16* __restrict__ B,
                                                     u16* __restrict__ Qh,
                                                     u16* __restrict__ Kh,
                                                     u16* __restrict__ Vt) {
  __shared__ __align__(16) u16 As[8192];
  __shared__ __align__(16) u16 Bs[8192];
  v4f acc[4][4];
  const int row0 = blockIdx.x * 128, col0 = blockIdx.y * 128;
  gemm_core(A, B, 1024, row0, col0, As, Bs, acc);
  const int tid = threadIdx.x, lane = tid & 63;
  const int wm = (tid >> 7) & 1, wn = (tid >> 6) & 1;
  const int ln = lane & 15, quad = lane >> 4;
  const int colbase = col0 + wn * 64;       // 64-aligned => one head per wave
  const int seg = colbase >> 10;            // 0=q 1=k 2=v
  const int h = (colbase & 1023) >> 6;
  if (seg < 2) {
    u16* dst = (seg == 0) ? Qh : Kh;
    const float oscl = (seg == 0) ? ATTN_SCL : 1.0f;
#pragma unroll
    for (int i = 0; i < 4; ++i) {
#pragma unroll
      for (int r = 0; r < 4; ++r) {
        int row = row0 + wm * 64 + i * 16 + quad * 4 + r;
        int b = row >> 11, t = row & 2047;
        size_t base = ((size_t)(b * 16 + h) * 2048 + t) * 64;
#pragma unroll
        for (int j = 0; j < 2; ++j) {
          int d1 = j * 16 + ln;  // 0..31
          float theta = exp2f((float)d1 * -0.4152410118609203f);  // 10000^(-d1/32)
          float sn, cs;
          fast_sincos((float)t * theta, &sn, &cs);
          float v1 = acc[i][j][r], v2 = acc[i][j + 2][r];
          dst[base + d1]      = f2bf((v1 * cs - v2 * sn) * oscl);
          dst[base + d1 + 32] = f2bf((v2 * cs + v1 * sn) * oscl);
        }
      }
    }
  } else {
#pragma unroll
    for (int i = 0; i < 4; ++i)
#pragma unroll
      for (int j = 0; j < 4; ++j) {
        int d = j * 16 + ln;
#pragma unroll
        for (int r = 0; r < 4; ++r) {
          int row = row0 + wm * 64 + i * 16 + quad * 4 + r;
          int b = row >> 11, t = row & 2047;
          Vt[((size_t)(b * 16 + h) * 64 + d) * 2048 + t] = f2bf(acc[i][j][r]);
        }
      }
  }
}

// ---------------- output GEMM: 128x64 tiles, 4 blocks/CU ----------------
__global__ __launch_bounds__(256, 4) void gemm_out_k(const u16* __restrict__ A,
                                                     const u16* __restrict__ B,
                                                     float* __restrict__ C) {
  __shared__ __align__(16) u16 As[128 * 64];  // 16 KB
  __shared__ __align__(16) u16 Bs[64 * 64];   //  8 KB
  const int tid = threadIdx.x;
  const int lane = tid & 63;
  const int wm = (tid >> 7) & 1;
  const int wn = (tid >> 6) & 1;
  const int ln = lane & 15, quad = lane >> 4;
  const int row0 = blockIdx.x * 128, col0 = blockIdx.y * 64;
  const int K = 1024;
  v4f acc[4][2];
#pragma unroll
  for (int i = 0; i < 4; ++i)
#pragma unroll
    for (int j = 0; j < 2; ++j) acc[i][j] = zero4();
  const int rA = tid >> 3;
  const int cA = (((tid & 7) ^ (rA & 7)) << 3);
  for (int kt = 0; kt < K; kt += 64) {
#pragma unroll
    for (int i = 0; i < 4; ++i)
      async16(A + (size_t)(row0 + i * 32 + rA) * K + kt + cA, As + i * 2048 + tid * 8);
#pragma unroll
    for (int i = 0; i < 2; ++i)
      async16(B + (size_t)(col0 + i * 32 + rA) * K + kt + cA, Bs + i * 2048 + tid * 8);
    __syncthreads();
#pragma unroll
    for (int kk = 0; kk < 2; ++kk) {
      const int go = (((kk * 4 + quad) ^ (ln & 7)) << 3);
      v8s af[4], bfr[2];
#pragma unroll
      for (int i = 0; i < 4; ++i)
        af[i] = *(const v8s*)(As + (wm * 64 + i * 16 + ln) * 64 + go);
#pragma unroll
      for (int j = 0; j < 2; ++j)
        bfr[j] = *(const v8s*)(Bs + (wn * 32 + j * 16 + ln) * 64 + go);
      __builtin_amdgcn_s_setprio(1);
#pragma unroll
      for (int i = 0; i < 4; ++i)
#pragma unroll
        for (int j = 0; j < 2; ++j)
          acc[i][j] = __builtin_amdgcn_mfma_f32_16x16x32_bf16(af[i], bfr[j], acc[i][j], 0, 0, 0);
      __builtin_amdgcn_s_setprio(0);
    }
    __syncthreads();
  }
#pragma unroll
  for (int i = 0; i < 4; ++i)
#pragma unroll
    for (int r = 0; r < 4; ++r) {
      int row = row0 + wm * 64 + i * 16 + quad * 4 + r;
#pragma unroll
      for (int j = 0; j < 2; ++j) {
        int col = col0 + wn * 32 + j * 16 + ln;
        C[(size_t)row * 1024 + col] = acc[i][j][r];
      }
    }
}

// ---------------- causal flash attention v8: fused q-phase pairs ----------------
// v7b counters: 1455 cyc/tile-slot vs ~400 useful -> latency-bound per tile.
// v8 fuses the two q-tiles (qtA=31-bx, qtB=bx) into ONE K/V staging pass:
// qtB's tile range [0,ntB) is a prefix of qtA's [0,ntA), so each staged tile
// serves both q-sets. Stagings/barriers/vmcnt drains: 33 -> 32-bx (avg 24.5,
// -26%), and each barrier interval holds TWO independent tile-computes (B's
// QK has no register dep on A's softmax/PV -> scheduler overlaps them).
// Ps WAR between A and B is ordered by the in-order DS pipe (same addresses).
// Numerics bitwise identical to v7b (same ops, same order per q-set).

template <bool MASKED>
__device__ __forceinline__ void flash_tile64(const u16* Ks, const u16* Vs, u16* Pw,
                                             const v8s aq[2], v4f od[4], float& l,
                                             int s0, int qrow, int ln, int quad,
                                             int swz) {
  v4f sc[4];
#pragma unroll
  for (int kf = 0; kf < 4; ++kf) sc[kf] = zero4();
#pragma unroll
  for (int kk = 0; kk < 2; ++kk) {
    const int go = (((kk * 4 + quad) ^ (ln & 7)) << 3);
    __builtin_amdgcn_s_setprio(1);
#pragma unroll
    for (int kf = 0; kf < 4; ++kf) {
      v8s ak = *(const v8s*)(Ks + (kf * 16 + ln) * 64 + go);
      sc[kf] = __builtin_amdgcn_mfma_f32_16x16x32_bf16(ak, aq[kk], sc[kf], 0, 0, 0);
    }
    __builtin_amdgcn_s_setprio(0);
  }
  float ls = 0.f;
#pragma unroll
  for (int kf = 0; kf < 4; ++kf) {
    float p[4];
#pragma unroll
    for (int r = 0; r < 4; ++r) {
      float v = sc[kf][r];
      if (MASKED) {
        int key = s0 + kf * 16 + quad * 4 + r;
        v = (key <= qrow) ? v : -3.0e38f;   // exp2 -> 0
      }
      p[r] = exp2f(v);
    }
    ls += (p[0] + p[1]) + (p[2] + p[3]);
    uint2 pk;
    pk.x = pk2bf(p[0], p[1]);
    pk.y = pk2bf(p[2], p[3]);
    *(uint2*)(Pw + ln * 64 + (((kf * 4 + quad) ^ swz) << 2)) = pk;
  }
  l += ls;
  // PV: per-wave P round-trip (lgkmcnt only, no barrier); stream V fragments
#pragma unroll
  for (int kk = 0; kk < 2; ++kk) {
    v8s bp = *(const v8s*)(Pw + ln * 64 + (((kk * 8 + quad * 2) ^ swz) << 2));
    const int go = (((kk * 4 + quad) ^ (ln & 7)) << 3);
    __builtin_amdgcn_s_setprio(1);
#pragma unroll
    for (int df = 0; df < 4; ++df) {
      v8s av = *(const v8s*)(Vs + (df * 16 + ln) * 64 + go);
      od[df] = __builtin_amdgcn_mfma_f32_16x16x32_bf16(av, bp, od[df], 0, 0, 0);
    }
    __builtin_amdgcn_s_setprio(0);
  }
}

__device__ __forceinline__ void flash_epilogue(float l, const v4f od[4], int q0,
                                               int b, int h, int ln, int quad,
                                               u16* __restrict__ O) {
  float lt = l;
  lt += __shfl_xor(lt, 16);
  lt += __shfl_xor(lt, 32);
  float inv = 1.0f / lt;
  int t = q0 + ln;
  size_t obase = ((size_t)b * 2048 + t) * 1024 + h * 64;
#pragma unroll
  for (int df = 0; df < 4; ++df) {
    ushort4 o;
    o.x = f2bf(od[df][0] * inv);
    o.y = f2bf(od[df][1] * inv);
    o.z = f2bf(od[df][2] * inv);
    o.w = f2bf(od[df][3] * inv);
    *(ushort4*)(O + obase + df * 16 + quad * 4) = o;
  }
}

__global__ __launch_bounds__(256, 4) void flash_k(const u16* __restrict__ Q,
                                                  const u16* __restrict__ Kh,
                                                  const u16* __restrict__ V,
                                                  u16* __restrict__ O) {
  __shared__ __align__(16) u16 Ks[2][4096];  // 2 x 8 KB, swizzled
  __shared__ __align__(16) u16 Vs[2][4096];  // 2 x 8 KB, swizzled
  __shared__ __align__(16) u16 Ps[4096];     // 8 KB (4 waves x 16 x 64, swizzled)
  const int tid = threadIdx.x;
  const int lane = tid & 63, w = tid >> 6;
  const int ln = lane & 15, quad = lane >> 4;
  const int swz = (lane & 7) << 1;           // even -> preserves 16B pairs
  const int bx = blockIdx.y;                 // 0..15
  const int bh = blockIdx.x;                 // bh on x: XCD-local K/V sharing
  const int b = bh >> 4, h = bh & 15;
  const size_t qoff = (size_t)bh * 2048 * 64;
  u16* Pw = Ps + w * 1024;

  const int rS = tid >> 3;
  const int cS = (((tid & 7) ^ (rS & 7)) << 3);   // swizzled source granule
  const u16* Kbase = Kh + qoff;
  const u16* Vbase = V + (size_t)bh * 131072;

  const int qtA = 31 - bx, qtB = bx;          // ntB <= ntA always (bx<16)
  const int ntA = qtA + 1, ntB = qtB + 1;
  const int q0A = qtA * 64 + w * 16, q0B = qtB * 64 + w * 16;
  const int qrowA = q0A + ln, qrowB = q0B + ln;
  v8s aqA[2], aqB[2];
#pragma unroll
  for (int kk = 0; kk < 2; ++kk) {
    aqA[kk] = *(const v8s*)(Q + qoff + (size_t)(q0A + ln) * 64 + kk * 32 + quad * 8);
    aqB[kk] = *(const v8s*)(Q + qoff + (size_t)(q0B + ln) * 64 + kk * 32 + quad * 8);
  }
  float lA = 0.f, lB = 0.f;
  v4f odA[4], odB[4];
#pragma unroll
  for (int df = 0; df < 4; ++df) { odA[df] = zero4(); odB[df] = zero4(); }

  // prologue: stage tile 0 into buffer 0
  {
    async16(Kbase + (size_t)rS * 64 + cS, Ks[0] + tid * 8);
    async16(Kbase + (size_t)(32 + rS) * 64 + cS, Ks[0] + 2048 + tid * 8);
    async16(Vbase + (size_t)rS * 2048 + cS, Vs[0] + tid * 8);
    async16(Vbase + (size_t)(rS + 32) * 2048 + cS, Vs[0] + 2048 + tid * 8);
  }
  for (int it = 0; it < ntA; ++it) {
    __syncthreads();  // drains prefetch of buf[it&1]; guards reuse of buf[(it+1)&1]
    if (it + 1 < ntA) {
      const int s1 = (it + 1) * 64;
      u16* kd = Ks[(it + 1) & 1];
      u16* vd = Vs[(it + 1) & 1];
      async16(Kbase + (size_t)(s1 + rS) * 64 + cS, kd + tid * 8);
      async16(Kbase + (size_t)(s1 + 32 + rS) * 64 + cS, kd + 2048 + tid * 8);
      async16(Vbase + (size_t)rS * 2048 + s1 + cS, vd + tid * 8);
      async16(Vbase + (size_t)(rS + 32) * 2048 + s1 + cS, vd + 2048 + tid * 8);
    }
    const int s0 = it * 64;
    const u16* Kc = Ks[it & 1];
    const u16* Vc = Vs[it & 1];
    if (it == ntA - 1)
      flash_tile64<true>(Kc, Vc, Pw, aqA, odA, lA, s0, qrowA, ln, quad, swz);
    else
      flash_tile64<false>(Kc, Vc, Pw, aqA, odA, lA, s0, qrowA, ln, quad, swz);
    if (it < ntB) {
      if (it == ntB - 1)
        flash_tile64<true>(Kc, Vc, Pw, aqB, odB, lB, s0, qrowB, ln, quad, swz);
      else
        flash_tile64<false>(Kc, Vc, Pw, aqB, odB, lB, s0, qrowB, ln, quad, swz);
    }
  }

  flash_epilogue(lA, odA, q0A, b, h, ln, quad, O);
  flash_epilogue(lB, odB, q0B, b, h, ln, quad, O);
}

extern "C" void kernel_launch(void* const* d_in, const int* in_sizes, int n_in,
                              void* d_out, int out_size, void* d_ws, size_t ws_size,
                              hipStream_t stream) {
  const float* x     = (const float*)d_in[0];
  const float* w_qkv = (const float*)d_in[1];
  const float* w_out = (const float*)d_in[2];
  float* out = (float*)d_out;
  char* ws = (char*)d_ws;
  u16* xb    = (u16*)(ws);              // 16 MB   [0, 16777216)
  u16* wqkvb = (u16*)(ws + 16777216);   // 6 MB    [16777216, 23068672)
  u16* woutb = (u16*)(ws + 23068672);   // 2 MB    [23068672, 25165824)
  u16* qh    = (u16*)(ws + 25165824);   // [64][2048][64]  16 MB
  u16* kh    = (u16*)(ws + 41943040);   // [64][2048][64]  16 MB
  u16* vt    = (u16*)(ws + 58720256);   // [64][64][2048]  16 MB
  u16* oa    = (u16*)(ws + 75497472);   // [8192][1024]    16 MB

  cast_all_k<<<12288, 256, 0, stream>>>(x, w_qkv, w_out, (u16*)ws);
  gemm_qkv_rope<<<dim3(64, 24), 256, 0, stream>>>(xb, wqkvb, qh, kh, vt);
  flash_k<<<dim3(64, 16), 256, 0, stream>>>(qh, kh, vt, oa);
  gemm_out_k<<<dim3(64, 16), 256, 0, stream>>>(oa, woutb, out);
}

// Round 5
// 266.929 us; speedup vs baseline: 1.1347x; 1.1347x over previous
//
#include <hip/hip_runtime.h>

typedef unsigned short u16;
typedef __attribute__((ext_vector_type(8))) short v8s;   // 8 x bf16 MFMA operand
typedef __attribute__((ext_vector_type(4))) float v4f;   // MFMA accumulator

__device__ __forceinline__ u16 f2bf(float f) {
  unsigned u = __float_as_uint(f);
  u += 0x7FFF + ((u >> 16) & 1);   // RNE
  return (u16)(u >> 16);
}

// pack two floats -> {hi.bf16, lo.bf16} u32 (round-half-up, fine at this scale)
__device__ __forceinline__ unsigned pk2bf(float lo, float hi) {
  unsigned a = __float_as_uint(lo) + 0x8000u;
  unsigned b = __float_as_uint(hi) + 0x8000u;
  return __builtin_amdgcn_perm(b, a, 0x07060302);
}

__device__ __forceinline__ v4f zero4() {
  v4f z; z[0] = 0.f; z[1] = 0.f; z[2] = 0.f; z[3] = 0.f; return z;
}

__device__ __forceinline__ void async16(const u16* g, u16* l) {
  __builtin_amdgcn_global_load_lds(
      (const __attribute__((address_space(1))) unsigned int*)g,
      (__attribute__((address_space(3))) unsigned int*)l, 16, 0, 0);
}

// reduce x to [-pi,pi] then native sin/cos (v_sin valid range)
__device__ __forceinline__ void fast_sincos(float x, float* s, float* c) {
  float k = rintf(x * 0.15915494309189535f);
  float r = __builtin_fmaf(k, -6.28125f, x);
  r = __builtin_fmaf(k, -0.0019353071795864769f, r);
  *s = __sinf(r);
  *c = __cosf(r);
}

#define ATTN_SCL (0.125f * 1.4426950408889634f)  // 1/sqrt(64) * log2(e), folded into Q

// ---------------- fused fp32 -> bf16 cast of all three inputs ----------------
// dst slots are contiguous in ws: xb [0,16M) | wqkvb [16M,22M) | woutb [22M,24M)
__global__ __launch_bounds__(256) void cast_all_k(const float* __restrict__ x,
                                                  const float* __restrict__ wq,
                                                  const float* __restrict__ wo,
                                                  u16* __restrict__ dst) {
  int i = blockIdx.x * 256 + threadIdx.x;
  const float4* s;
  int si;
  if (i < 2097152) { s = (const float4*)x;  si = i; }
  else if (i < 2883584) { s = (const float4*)wq; si = i - 2097152; }
  else { s = (const float4*)wo; si = i - 2883584; }
  float4 v = s[si];
  ((ushort4*)dst)[i] = make_ushort4(f2bf(v.x), f2bf(v.y), f2bf(v.z), f2bf(v.w));
}

// LDS bank swizzle: 16B granule g of row r lives at slot g^(r&7).
// Staging (global_load_lds is lane-contiguous on the LDS side): lane loads
// global granule (slot ^ (row&7)) so slot s holds data granule s^(r&7).

// ---------------- 128x128 GEMM mainloop (qkv) ----------------
// C(128x128) = A[M,K] @ B[N,K]^T   (both bf16 row-major, K multiple of 64)
__device__ __forceinline__ void gemm_core(const u16* __restrict__ A,
                                          const u16* __restrict__ B, int K,
                                          int row0, int col0, u16* As, u16* Bs,
                                          v4f acc[4][4]) {
  const int tid = threadIdx.x;
  const int lane = tid & 63;
  const int wm = (tid >> 7) & 1;
  const int wn = (tid >> 6) & 1;
  const int ln = lane & 15, quad = lane >> 4;
#pragma unroll
  for (int i = 0; i < 4; ++i)
#pragma unroll
    for (int j = 0; j < 4; ++j) acc[i][j] = zero4();
  const int rA = tid >> 3;
  const int cA = (((tid & 7) ^ (rA & 7)) << 3);   // swizzled source granule
  for (int kt = 0; kt < K; kt += 64) {
#pragma unroll
    for (int i = 0; i < 4; ++i) {
      async16(A + (size_t)(row0 + i * 32 + rA) * K + kt + cA, As + i * 2048 + tid * 8);
      async16(B + (size_t)(col0 + i * 32 + rA) * K + kt + cA, Bs + i * 2048 + tid * 8);
    }
    __syncthreads();
#pragma unroll
    for (int kk = 0; kk < 2; ++kk) {
      const int go = (((kk * 4 + quad) ^ (ln & 7)) << 3);  // swizzled read granule
      v8s af[4], bfr[4];
#pragma unroll
      for (int i = 0; i < 4; ++i) {
        af[i]  = *(const v8s*)(As + (wm * 64 + i * 16 + ln) * 64 + go);
        bfr[i] = *(const v8s*)(Bs + (wn * 64 + i * 16 + ln) * 64 + go);
      }
      __builtin_amdgcn_s_setprio(1);
#pragma unroll
      for (int i = 0; i < 4; ++i)
#pragma unroll
        for (int j = 0; j < 4; ++j)
          acc[i][j] = __builtin_amdgcn_mfma_f32_16x16x32_bf16(af[i], bfr[j], acc[i][j], 0, 0, 0);
      __builtin_amdgcn_s_setprio(0);
    }
    __syncthreads();
  }
}

// ---------------- QKV GEMM + fused RoPE/reshape epilogue ----------------
// q gets the softmax scale folded in (scale commutes with rotation)
__global__ __launch_bounds__(256) void gemm_qkv_rope(const u16* __restrict__ A,
                                                     const u16* __restrict__ B,
                                                     u16* __restrict__ Qh,
                                                     u16* __restrict__ Kh,
                                                     u16* __restrict__ Vt) {
  __shared__ __align__(16) u16 As[8192];
  __shared__ __align__(16) u16 Bs[8192];
  v4f acc[4][4];
  const int row0 = blockIdx.x * 128, col0 = blockIdx.y * 128;
  gemm_core(A, B, 1024, row0, col0, As, Bs, acc);
  const int tid = threadIdx.x, lane = tid & 63;
  const int wm = (tid >> 7) & 1, wn = (tid >> 6) & 1;
  const int ln = lane & 15, quad = lane >> 4;
  const int colbase = col0 + wn * 64;       // 64-aligned => one head per wave
  const int seg = colbase >> 10;            // 0=q 1=k 2=v
  const int h = (colbase & 1023) >> 6;
  if (seg < 2) {
    u16* dst = (seg == 0) ? Qh : Kh;
    const float oscl = (seg == 0) ? ATTN_SCL : 1.0f;
#pragma unroll
    for (int i = 0; i < 4; ++i) {
#pragma unroll
      for (int r = 0; r < 4; ++r) {
        int row = row0 + wm * 64 + i * 16 + quad * 4 + r;
        int b = row >> 11, t = row & 2047;
        size_t base = ((size_t)(b * 16 + h) * 2048 + t) * 64;
#pragma unroll
        for (int j = 0; j < 2; ++j) {
          int d1 = j * 16 + ln;  // 0..31
          float theta = exp2f((float)d1 * -0.4152410118609203f);  // 10000^(-d1/32)
          float sn, cs;
          fast_sincos((float)t * theta, &sn, &cs);
          float v1 = acc[i][j][r], v2 = acc[i][j + 2][r];
          dst[base + d1]      = f2bf((v1 * cs - v2 * sn) * oscl);
          dst[base + d1 + 32] = f2bf((v2 * cs + v1 * sn) * oscl);
        }
      }
    }
  } else {
#pragma unroll
    for (int i = 0; i < 4; ++i)
#pragma unroll
      for (int j = 0; j < 4; ++j) {
        int d = j * 16 + ln;
#pragma unroll
        for (int r = 0; r < 4; ++r) {
          int row = row0 + wm * 64 + i * 16 + quad * 4 + r;
          int b = row >> 11, t = row & 2047;
          Vt[((size_t)(b * 16 + h) * 64 + d) * 2048 + t] = f2bf(acc[i][j][r]);
        }
      }
  }
}

// ---------------- output GEMM: 128x64 tiles, 4 blocks/CU ----------------
__global__ __launch_bounds__(256, 4) void gemm_out_k(const u16* __restrict__ A,
                                                     const u16* __restrict__ B,
                                                     float* __restrict__ C) {
  __shared__ __align__(16) u16 As[128 * 64];  // 16 KB
  __shared__ __align__(16) u16 Bs[64 * 64];   //  8 KB
  const int tid = threadIdx.x;
  const int lane = tid & 63;
  const int wm = (tid >> 7) & 1;
  const int wn = (tid >> 6) & 1;
  const int ln = lane & 15, quad = lane >> 4;
  const int row0 = blockIdx.x * 128, col0 = blockIdx.y * 64;
  const int K = 1024;
  v4f acc[4][2];
#pragma unroll
  for (int i = 0; i < 4; ++i)
#pragma unroll
    for (int j = 0; j < 2; ++j) acc[i][j] = zero4();
  const int rA = tid >> 3;
  const int cA = (((tid & 7) ^ (rA & 7)) << 3);
  for (int kt = 0; kt < K; kt += 64) {
#pragma unroll
    for (int i = 0; i < 4; ++i)
      async16(A + (size_t)(row0 + i * 32 + rA) * K + kt + cA, As + i * 2048 + tid * 8);
#pragma unroll
    for (int i = 0; i < 2; ++i)
      async16(B + (size_t)(col0 + i * 32 + rA) * K + kt + cA, Bs + i * 2048 + tid * 8);
    __syncthreads();
#pragma unroll
    for (int kk = 0; kk < 2; ++kk) {
      const int go = (((kk * 4 + quad) ^ (ln & 7)) << 3);
      v8s af[4], bfr[2];
#pragma unroll
      for (int i = 0; i < 4; ++i)
        af[i] = *(const v8s*)(As + (wm * 64 + i * 16 + ln) * 64 + go);
#pragma unroll
      for (int j = 0; j < 2; ++j)
        bfr[j] = *(const v8s*)(Bs + (wn * 32 + j * 16 + ln) * 64 + go);
      __builtin_amdgcn_s_setprio(1);
#pragma unroll
      for (int i = 0; i < 4; ++i)
#pragma unroll
        for (int j = 0; j < 2; ++j)
          acc[i][j] = __builtin_amdgcn_mfma_f32_16x16x32_bf16(af[i], bfr[j], acc[i][j], 0, 0, 0);
      __builtin_amdgcn_s_setprio(0);
    }
    __syncthreads();
  }
#pragma unroll
  for (int i = 0; i < 4; ++i)
#pragma unroll
    for (int r = 0; r < 4; ++r) {
      int row = row0 + wm * 64 + i * 16 + quad * 4 + r;
#pragma unroll
      for (int j = 0; j < 2; ++j) {
        int col = col0 + wn * 32 + j * 16 + ln;
        C[(size_t)row * 1024 + col] = acc[i][j][r];
      }
    }
}

// ---------------- causal flash attention v9: wave-split q-pair ----------------
// v8 post-mortem: fusing qtA/qtB in ONE wave doubled live state (aq/od/sc x2)
// -> VGPR spill (WRITE_SIZE 16->73 MB, MfmaUtil 0.6%). v9 keeps the shared
// K/V staging pass (33 -> 32-bx barrier intervals, -26% drains) but assigns
// qtA to waves 0-3 and qtB to waves 4-7 of a 512-thread block: per-wave
// register state is exactly v7b's (no spill possible), and each barrier
// interval holds two independent wave-groups' compute (TLP overlap).
// LDS 48 KB -> 3 blocks/CU = 24 waves/CU (vs v7b's 16). B-waves idle at
// barriers for ntA-ntB intervals; effective busy waves ~= v7b, minus 26%
// barrier-drain stalls. Numerics per q-set identical to v7b.

template <bool MASKED>
__device__ __forceinline__ void flash_tile64(const u16* Ks, const u16* Vs, u16* Pw,
                                             const v8s aq[2], v4f od[4], float& l,
                                             int s0, int qrow, int ln, int quad,
                                             int swz) {
  v4f sc[4];
#pragma unroll
  for (int kf = 0; kf < 4; ++kf) sc[kf] = zero4();
#pragma unroll
  for (int kk = 0; kk < 2; ++kk) {
    const int go = (((kk * 4 + quad) ^ (ln & 7)) << 3);
    __builtin_amdgcn_s_setprio(1);
#pragma unroll
    for (int kf = 0; kf < 4; ++kf) {
      v8s ak = *(const v8s*)(Ks + (kf * 16 + ln) * 64 + go);
      sc[kf] = __builtin_amdgcn_mfma_f32_16x16x32_bf16(ak, aq[kk], sc[kf], 0, 0, 0);
    }
    __builtin_amdgcn_s_setprio(0);
  }
  float ls = 0.f;
#pragma unroll
  for (int kf = 0; kf < 4; ++kf) {
    float p[4];
#pragma unroll
    for (int r = 0; r < 4; ++r) {
      float v = sc[kf][r];
      if (MASKED) {
        int key = s0 + kf * 16 + quad * 4 + r;
        v = (key <= qrow) ? v : -3.0e38f;   // exp2 -> 0
      }
      p[r] = exp2f(v);
    }
    ls += (p[0] + p[1]) + (p[2] + p[3]);
    uint2 pk;
    pk.x = pk2bf(p[0], p[1]);
    pk.y = pk2bf(p[2], p[3]);
    *(uint2*)(Pw + ln * 64 + (((kf * 4 + quad) ^ swz) << 2)) = pk;
  }
  l += ls;
  // PV: per-wave P round-trip (lgkmcnt only, no barrier); stream V fragments
#pragma unroll
  for (int kk = 0; kk < 2; ++kk) {
    v8s bp = *(const v8s*)(Pw + ln * 64 + (((kk * 8 + quad * 2) ^ swz) << 2));
    const int go = (((kk * 4 + quad) ^ (ln & 7)) << 3);
    __builtin_amdgcn_s_setprio(1);
#pragma unroll
    for (int df = 0; df < 4; ++df) {
      v8s av = *(const v8s*)(Vs + (df * 16 + ln) * 64 + go);
      od[df] = __builtin_amdgcn_mfma_f32_16x16x32_bf16(av, bp, od[df], 0, 0, 0);
    }
    __builtin_amdgcn_s_setprio(0);
  }
}

__global__ __launch_bounds__(512, 6) void flash_k(const u16* __restrict__ Q,
                                                  const u16* __restrict__ Kh,
                                                  const u16* __restrict__ V,
                                                  u16* __restrict__ O) {
  __shared__ __align__(16) u16 Ks[2][4096];  // 2 x 8 KB, swizzled
  __shared__ __align__(16) u16 Vs[2][4096];  // 2 x 8 KB, swizzled
  __shared__ __align__(16) u16 Ps[8192];     // 16 KB (8 waves x 16 x 64, swizzled)
  const int tid = threadIdx.x;
  const int lane = tid & 63, w = tid >> 6;   // w in [0,8)
  const int g = w >> 2, wl = w & 3;          // group (0=A,1=B), wave-local
  const int ln = lane & 15, quad = lane >> 4;
  const int swz = (lane & 7) << 1;           // even -> preserves 16B pairs
  const int bx = blockIdx.y;                 // 0..15
  const int bh = blockIdx.x;                 // bh on x: XCD-local K/V sharing
  const int b = bh >> 4, h = bh & 15;
  const size_t qoff = (size_t)bh * 2048 * 64;
  u16* Pw = Ps + w * 1024;

  const int rS = tid >> 3;                   // 0..63: one K row + one V row per thread
  const int cS = (((tid & 7) ^ (rS & 7)) << 3);   // swizzled source granule
  const u16* Kbase = Kh + qoff;
  const u16* Vbase = V + (size_t)bh * 131072;

  const int qt = g ? bx : 31 - bx;           // A: 16..31, B: 0..15 (disjoint)
  const int nt = qt + 1;
  const int ntA = 32 - bx;                   // loop bound = A-group's tile count
  const int q0 = qt * 64 + wl * 16;
  const int qrow = q0 + ln;
  v8s aq[2];
#pragma unroll
  for (int kk = 0; kk < 2; ++kk)
    aq[kk] = *(const v8s*)(Q + qoff + (size_t)(q0 + ln) * 64 + kk * 32 + quad * 8);
  float l = 0.f;
  v4f od[4];
#pragma unroll
  for (int df = 0; df < 4; ++df) od[df] = zero4();

  // prologue: stage tile 0 into buffer 0 (512 threads: 1 K + 1 V load each)
  async16(Kbase + (size_t)rS * 64 + cS, Ks[0] + tid * 8);
  async16(Vbase + (size_t)rS * 2048 + cS, Vs[0] + tid * 8);

  for (int it = 0; it < ntA; ++it) {
    __syncthreads();  // drains prefetch of buf[it&1]; guards reuse of buf[(it+1)&1]
    if (it + 1 < ntA) {
      const int s1 = (it + 1) * 64;
      async16(Kbase + (size_t)(s1 + rS) * 64 + cS, Ks[(it + 1) & 1] + tid * 8);
      async16(Vbase + (size_t)rS * 2048 + s1 + cS, Vs[(it + 1) & 1] + tid * 8);
    }
    if (it < nt) {
      const int s0 = it * 64;
      if (it == nt - 1)
        flash_tile64<true>(Ks[it & 1], Vs[it & 1], Pw, aq, od, l, s0, qrow, ln, quad, swz);
      else
        flash_tile64<false>(Ks[it & 1], Vs[it & 1], Pw, aq, od, l, s0, qrow, ln, quad, swz);
    }
  }

  float lt = l;
  lt += __shfl_xor(lt, 16);
  lt += __shfl_xor(lt, 32);
  float inv = 1.0f / lt;
  int t = q0 + ln;
  size_t obase = ((size_t)b * 2048 + t) * 1024 + h * 64;
#pragma unroll
  for (int df = 0; df < 4; ++df) {
    ushort4 o;
    o.x = f2bf(od[df][0] * inv);
    o.y = f2bf(od[df][1] * inv);
    o.z = f2bf(od[df][2] * inv);
    o.w = f2bf(od[df][3] * inv);
    *(ushort4*)(O + obase + df * 16 + quad * 4) = o;
  }
}

extern "C" void kernel_launch(void* const* d_in, const int* in_sizes, int n_in,
                              void* d_out, int out_size, void* d_ws, size_t ws_size,
                              hipStream_t stream) {
  const float* x     = (const float*)d_in[0];
  const float* w_qkv = (const float*)d_in[1];
  const float* w_out = (const float*)d_in[2];
  float* out = (float*)d_out;
  char* ws = (char*)d_ws;
  u16* xb    = (u16*)(ws);              // 16 MB   [0, 16777216)
  u16* wqkvb = (u16*)(ws + 16777216);   // 6 MB    [16777216, 23068672)
  u16* woutb = (u16*)(ws + 23068672);   // 2 MB    [23068672, 25165824)
  u16* qh    = (u16*)(ws + 25165824);   // [64][2048][64]  16 MB
  u16* kh    = (u16*)(ws + 41943040);   // [64][2048][64]  16 MB
  u16* vt    = (u16*)(ws + 58720256);   // [64][64][2048]  16 MB
  u16* oa    = (u16*)(ws + 75497472);   // [8192][1024]    16 MB

  cast_all_k<<<12288, 256, 0, stream>>>(x, w_qkv, w_out, (u16*)ws);
  gemm_qkv_rope<<<dim3(64, 24), 256, 0, stream>>>(xb, wqkvb, qh, kh, vt);
  flash_k<<<dim3(64, 16), 512, 0, stream>>>(qh, kh, vt, oa);
  gemm_out_k<<<dim3(64, 16), 256, 0, stream>>>(oa, woutb, out);
}

// Round 7
// 249.084 us; speedup vs baseline: 1.2160x; 1.0716x over previous
//
#include <hip/hip_runtime.h>

typedef unsigned short u16;
typedef __attribute__((ext_vector_type(8))) short v8s;   // 8 x bf16 MFMA operand
typedef __attribute__((ext_vector_type(4))) float v4f;   // MFMA accumulator

__device__ __forceinline__ u16 f2bf(float f) {
  unsigned u = __float_as_uint(f);
  u += 0x7FFF + ((u >> 16) & 1);   // RNE
  return (u16)(u >> 16);
}

// pack two floats -> {hi.bf16, lo.bf16} u32 (round-half-up, fine at this scale)
__device__ __forceinline__ unsigned pk2bf(float lo, float hi) {
  unsigned a = __float_as_uint(lo) + 0x8000u;
  unsigned b = __float_as_uint(hi) + 0x8000u;
  return __builtin_amdgcn_perm(b, a, 0x07060302);
}

__device__ __forceinline__ v4f zero4() {
  v4f z; z[0] = 0.f; z[1] = 0.f; z[2] = 0.f; z[3] = 0.f; return z;
}

__device__ __forceinline__ void async16(const u16* g, u16* l) {
  __builtin_amdgcn_global_load_lds(
      (const __attribute__((address_space(1))) unsigned int*)g,
      (__attribute__((address_space(3))) unsigned int*)l, 16, 0, 0);
}

// reduce x to [-pi,pi] then native sin/cos (v_sin valid range)
__device__ __forceinline__ void fast_sincos(float x, float* s, float* c) {
  float k = rintf(x * 0.15915494309189535f);
  float r = __builtin_fmaf(k, -6.28125f, x);
  r = __builtin_fmaf(k, -0.0019353071795864769f, r);
  *s = __sinf(r);
  *c = __cosf(r);
}

#define ATTN_SCL (0.125f * 1.4426950408889634f)  // 1/sqrt(64) * log2(e), folded into Q

// ---------------- fused fp32 -> bf16 cast of all three inputs ----------------
// dst slots are contiguous in ws: xb [0,16M) | wqkvb [16M,22M) | woutb [22M,24M)
__global__ __launch_bounds__(256) void cast_all_k(const float* __restrict__ x,
                                                  const float* __restrict__ wq,
                                                  const float* __restrict__ wo,
                                                  u16* __restrict__ dst) {
  int i = blockIdx.x * 256 + threadIdx.x;
  const float4* s;
  int si;
  if (i < 2097152) { s = (const float4*)x;  si = i; }
  else if (i < 2883584) { s = (const float4*)wq; si = i - 2097152; }
  else { s = (const float4*)wo; si = i - 2883584; }
  float4 v = s[si];
  ((ushort4*)dst)[i] = make_ushort4(f2bf(v.x), f2bf(v.y), f2bf(v.z), f2bf(v.w));
}

// LDS bank swizzle: 16B granule g of row r lives at slot g^(r&7).
// Staging (global_load_lds is lane-contiguous on the LDS side): lane loads
// global granule (slot ^ (row&7)) so slot s holds data granule s^(r&7).

// ---------------- 128x128 GEMM mainloop (qkv) ----------------
// C(128x128) = A[M,K] @ B[N,K]^T   (both bf16 row-major, K multiple of 64)
__device__ __forceinline__ void gemm_core(const u16* __restrict__ A,
                                          const u16* __restrict__ B, int K,
                                          int row0, int col0, u16* As, u16* Bs,
                                          v4f acc[4][4]) {
  const int tid = threadIdx.x;
  const int lane = tid & 63;
  const int wm = (tid >> 7) & 1;
  const int wn = (tid >> 6) & 1;
  const int ln = lane & 15, quad = lane >> 4;
#pragma unroll
  for (int i = 0; i < 4; ++i)
#pragma unroll
    for (int j = 0; j < 4; ++j) acc[i][j] = zero4();
  const int rA = tid >> 3;
  const int cA = (((tid & 7) ^ (rA & 7)) << 3);   // swizzled source granule
  for (int kt = 0; kt < K; kt += 64) {
#pragma unroll
    for (int i = 0; i < 4; ++i) {
      async16(A + (size_t)(row0 + i * 32 + rA) * K + kt + cA, As + i * 2048 + tid * 8);
      async16(B + (size_t)(col0 + i * 32 + rA) * K + kt + cA, Bs + i * 2048 + tid * 8);
    }
    __syncthreads();
#pragma unroll
    for (int kk = 0; kk < 2; ++kk) {
      const int go = (((kk * 4 + quad) ^ (ln & 7)) << 3);  // swizzled read granule
      v8s af[4], bfr[4];
#pragma unroll
      for (int i = 0; i < 4; ++i) {
        af[i]  = *(const v8s*)(As + (wm * 64 + i * 16 + ln) * 64 + go);
        bfr[i] = *(const v8s*)(Bs + (wn * 64 + i * 16 + ln) * 64 + go);
      }
      __builtin_amdgcn_s_setprio(1);
#pragma unroll
      for (int i = 0; i < 4; ++i)
#pragma unroll
        for (int j = 0; j < 4; ++j)
          acc[i][j] = __builtin_amdgcn_mfma_f32_16x16x32_bf16(af[i], bfr[j], acc[i][j], 0, 0, 0);
      __builtin_amdgcn_s_setprio(0);
    }
    __syncthreads();
  }
}

// ---------------- QKV GEMM + fused RoPE/reshape epilogue ----------------
// q gets the softmax scale folded in (scale commutes with rotation)
__global__ __launch_bounds__(256) void gemm_qkv_rope(const u16* __restrict__ A,
                                                     const u16* __restrict__ B,
                                                     u16* __restrict__ Qh,
                                                     u16* __restrict__ Kh,
                                                     u16* __restrict__ Vt) {
  __shared__ __align__(16) u16 As[8192];
  __shared__ __align__(16) u16 Bs[8192];
  v4f acc[4][4];
  const int row0 = blockIdx.x * 128, col0 = blockIdx.y * 128;
  gemm_core(A, B, 1024, row0, col0, As, Bs, acc);
  const int tid = threadIdx.x, lane = tid & 63;
  const int wm = (tid >> 7) & 1, wn = (tid >> 6) & 1;
  const int ln = lane & 15, quad = lane >> 4;
  const int colbase = col0 + wn * 64;       // 64-aligned => one head per wave
  const int seg = colbase >> 10;            // 0=q 1=k 2=v
  const int h = (colbase & 1023) >> 6;
  if (seg < 2) {
    u16* dst = (seg == 0) ? Qh : Kh;
    const float oscl = (seg == 0) ? ATTN_SCL : 1.0f;
#pragma unroll
    for (int i = 0; i < 4; ++i) {
#pragma unroll
      for (int r = 0; r < 4; ++r) {
        int row = row0 + wm * 64 + i * 16 + quad * 4 + r;
        int b = row >> 11, t = row & 2047;
        size_t base = ((size_t)(b * 16 + h) * 2048 + t) * 64;
#pragma unroll
        for (int j = 0; j < 2; ++j) {
          int d1 = j * 16 + ln;  // 0..31
          float theta = exp2f((float)d1 * -0.4152410118609203f);  // 10000^(-d1/32)
          float sn, cs;
          fast_sincos((float)t * theta, &sn, &cs);
          float v1 = acc[i][j][r], v2 = acc[i][j + 2][r];
          dst[base + d1]      = f2bf((v1 * cs - v2 * sn) * oscl);
          dst[base + d1 + 32] = f2bf((v2 * cs + v1 * sn) * oscl);
        }
      }
    }
  } else {
#pragma unroll
    for (int i = 0; i < 4; ++i)
#pragma unroll
      for (int j = 0; j < 4; ++j) {
        int d = j * 16 + ln;
#pragma unroll
        for (int r = 0; r < 4; ++r) {
          int row = row0 + wm * 64 + i * 16 + quad * 4 + r;
          int b = row >> 11, t = row & 2047;
          Vt[((size_t)(b * 16 + h) * 64 + d) * 2048 + t] = f2bf(acc[i][j][r]);
        }
      }
  }
}

// ---------------- output GEMM: 128x64 tiles, 4 blocks/CU ----------------
__global__ __launch_bounds__(256, 4) void gemm_out_k(const u16* __restrict__ A,
                                                     const u16* __restrict__ B,
                                                     float* __restrict__ C) {
  __shared__ __align__(16) u16 As[128 * 64];  // 16 KB
  __shared__ __align__(16) u16 Bs[64 * 64];   //  8 KB
  const int tid = threadIdx.x;
  const int lane = tid & 63;
  const int wm = (tid >> 7) & 1;
  const int wn = (tid >> 6) & 1;
  const int ln = lane & 15, quad = lane >> 4;
  const int row0 = blockIdx.x * 128, col0 = blockIdx.y * 64;
  const int K = 1024;
  v4f acc[4][2];
#pragma unroll
  for (int i = 0; i < 4; ++i)
#pragma unroll
    for (int j = 0; j < 2; ++j) acc[i][j] = zero4();
  const int rA = tid >> 3;
  const int cA = (((tid & 7) ^ (rA & 7)) << 3);
  for (int kt = 0; kt < K; kt += 64) {
#pragma unroll
    for (int i = 0; i < 4; ++i)
      async16(A + (size_t)(row0 + i * 32 + rA) * K + kt + cA, As + i * 2048 + tid * 8);
#pragma unroll
    for (int i = 0; i < 2; ++i)
      async16(B + (size_t)(col0 + i * 32 + rA) * K + kt + cA, Bs + i * 2048 + tid * 8);
    __syncthreads();
#pragma unroll
    for (int kk = 0; kk < 2; ++kk) {
      const int go = (((kk * 4 + quad) ^ (ln & 7)) << 3);
      v8s af[4], bfr[2];
#pragma unroll
      for (int i = 0; i < 4; ++i)
        af[i] = *(const v8s*)(As + (wm * 64 + i * 16 + ln) * 64 + go);
#pragma unroll
      for (int j = 0; j < 2; ++j)
        bfr[j] = *(const v8s*)(Bs + (wn * 32 + j * 16 + ln) * 64 + go);
      __builtin_amdgcn_s_setprio(1);
#pragma unroll
      for (int i = 0; i < 4; ++i)
#pragma unroll
        for (int j = 0; j < 2; ++j)
          acc[i][j] = __builtin_amdgcn_mfma_f32_16x16x32_bf16(af[i], bfr[j], acc[i][j], 0, 0, 0);
      __builtin_amdgcn_s_setprio(0);
    }
    __syncthreads();
  }
#pragma unroll
  for (int i = 0; i < 4; ++i)
#pragma unroll
    for (int r = 0; r < 4; ++r) {
      int row = row0 + wm * 64 + i * 16 + quad * 4 + r;
#pragma unroll
      for (int j = 0; j < 2; ++j) {
        int col = col0 + wn * 32 + j * 16 + ln;
        C[(size_t)row * 1024 + col] = acc[i][j][r];
      }
    }
}

// ---------------- causal flash attention v10: 128-q blocks ----------------
// v9 post-mortem: wider barriers (8 waves) with an idle B-group regressed;
// occupancy is not the lever. v10 amortizes instead: each block covers 128
// q-rows (4 waves x two 16-row slices), so one staged K/V tile serves 2x the
// q-work. Intervals/head: 528 -> 272 (-48%); K/V global traffic halved; K and
// V fragments (ak/av) are held in registers across both slices (LDS reads
// 18 -> 14 per slice); slice1's QK is register-only and independent of
// slice0's softmax/PV -> in-wave MFMA/VALU overlap. launch_bounds(256,2)
// gives a 256-VGPR cap (state ~170, spill impossible); grid residency is
// 2 blocks/CU regardless (512 blocks). Per-slice numerics identical to v7b.

template <bool MASKED>
__device__ __forceinline__ void qk_sm_pv(const v8s ak[2][4], const v8s av[2][4],
                                         u16* Pw, const v8s aq[2], v4f od[4],
                                         float& l, int s0, int qrow, int ln,
                                         int quad, int swz) {
  v4f sc[4];
#pragma unroll
  for (int kf = 0; kf < 4; ++kf) sc[kf] = zero4();
#pragma unroll
  for (int kk = 0; kk < 2; ++kk) {
    __builtin_amdgcn_s_setprio(1);
#pragma unroll
    for (int kf = 0; kf < 4; ++kf)
      sc[kf] = __builtin_amdgcn_mfma_f32_16x16x32_bf16(ak[kk][kf], aq[kk], sc[kf], 0, 0, 0);
    __builtin_amdgcn_s_setprio(0);
  }
  float ls = 0.f;
#pragma unroll
  for (int kf = 0; kf < 4; ++kf) {
    float p[4];
#pragma unroll
    for (int r = 0; r < 4; ++r) {
      float v = sc[kf][r];
      if (MASKED) {
        int key = s0 + kf * 16 + quad * 4 + r;
        v = (key <= qrow) ? v : -3.0e38f;   // exp2 -> 0
      }
      p[r] = exp2f(v);
    }
    ls += (p[0] + p[1]) + (p[2] + p[3]);
    uint2 pk;
    pk.x = pk2bf(p[0], p[1]);
    pk.y = pk2bf(p[2], p[3]);
    *(uint2*)(Pw + ln * 64 + (((kf * 4 + quad) ^ swz) << 2)) = pk;
  }
  l += ls;
  // PV: per-wave P round-trip (lgkmcnt only, no barrier); V frags from regs
#pragma unroll
  for (int kk = 0; kk < 2; ++kk) {
    v8s bp = *(const v8s*)(Pw + ln * 64 + (((kk * 8 + quad * 2) ^ swz) << 2));
    __builtin_amdgcn_s_setprio(1);
#pragma unroll
    for (int df = 0; df < 4; ++df)
      od[df] = __builtin_amdgcn_mfma_f32_16x16x32_bf16(av[kk][df], bp, od[df], 0, 0, 0);
    __builtin_amdgcn_s_setprio(0);
  }
}

__device__ __forceinline__ void flash_epi(float l, const v4f od[4], int t,
                                          int b, int h, int quad,
                                          u16* __restrict__ O) {
  float lt = l;
  lt += __shfl_xor(lt, 16);
  lt += __shfl_xor(lt, 32);
  float inv = 1.0f / lt;
  size_t obase = ((size_t)b * 2048 + t) * 1024 + h * 64;
#pragma unroll
  for (int df = 0; df < 4; ++df) {
    ushort4 o;
    o.x = f2bf(od[df][0] * inv);
    o.y = f2bf(od[df][1] * inv);
    o.z = f2bf(od[df][2] * inv);
    o.w = f2bf(od[df][3] * inv);
    *(ushort4*)(O + obase + df * 16 + quad * 4) = o;
  }
}

__global__ __launch_bounds__(256, 2) void flash_k(const u16* __restrict__ Q,
                                                  const u16* __restrict__ Kh,
                                                  const u16* __restrict__ V,
                                                  u16* __restrict__ O) {
  __shared__ __align__(16) u16 Ks[2][4096];  // 2 x 8 KB, swizzled
  __shared__ __align__(16) u16 Vs[2][4096];  // 2 x 8 KB, swizzled
  __shared__ __align__(16) u16 Ps[4096];     // 8 KB (4 waves x 2 KB, swizzled)
  const int tid = threadIdx.x;
  const int lane = tid & 63, w = tid >> 6;
  const int ln = lane & 15, quad = lane >> 4;
  const int swz = (lane & 7) << 1;           // even -> preserves 16B pairs
  const int by = blockIdx.y;                 // 0..7
  const int bh = blockIdx.x;                 // bh on x: XCD-local K/V sharing
  const int b = bh >> 4, h = bh & 15;
  const size_t qoff = (size_t)bh * 2048 * 64;
  u16* Pw = Ps + w * 1024;

  const int rS = tid >> 3;                   // 0..31
  const int cS = (((tid & 7) ^ (rS & 7)) << 3);   // swizzled source granule
  const u16* Kbase = Kh + qoff;
  const u16* Vbase = V + (size_t)bh * 131072;

#pragma unroll
  for (int ph = 0; ph < 2; ++ph) {
    const int qx = ph ? by : 15 - by;        // q-block of 128 rows
    const int nt = 2 * qx + 2;               // k-tiles needed by this q-block
    const int diag = 2 * qx + (w >> 1);      // this wave's diagonal tile (both slices)
    const int S0 = qx * 128 + w * 32;        // slice0 rows S0..S0+15, slice1 +16
    const int qrow0 = S0 + ln, qrow1 = S0 + 16 + ln;
    v8s aq0[2], aq1[2];
#pragma unroll
    for (int kk = 0; kk < 2; ++kk) {
      aq0[kk] = *(const v8s*)(Q + qoff + (size_t)(S0 + ln) * 64 + kk * 32 + quad * 8);
      aq1[kk] = *(const v8s*)(Q + qoff + (size_t)(S0 + 16 + ln) * 64 + kk * 32 + quad * 8);
    }
    float l0 = 0.f, l1 = 0.f;
    v4f od0[4], od1[4];
#pragma unroll
    for (int df = 0; df < 4; ++df) { od0[df] = zero4(); od1[df] = zero4(); }

    // prologue: stage tile 0 into buffer 0
    {
      async16(Kbase + (size_t)rS * 64 + cS, Ks[0] + tid * 8);
      async16(Kbase + (size_t)(32 + rS) * 64 + cS, Ks[0] + 2048 + tid * 8);
      async16(Vbase + (size_t)rS * 2048 + cS, Vs[0] + tid * 8);
      async16(Vbase + (size_t)(rS + 32) * 2048 + cS, Vs[0] + 2048 + tid * 8);
    }
    for (int it = 0; it < nt; ++it) {
      __syncthreads();  // drains prefetch of buf[it&1]; guards reuse of buf[(it+1)&1]
      if (it + 1 < nt) {
        const int s1 = (it + 1) * 64;
        u16* kd = Ks[(it + 1) & 1];
        u16* vd = Vs[(it + 1) & 1];
        async16(Kbase + (size_t)(s1 + rS) * 64 + cS, kd + tid * 8);
        async16(Kbase + (size_t)(s1 + 32 + rS) * 64 + cS, kd + 2048 + tid * 8);
        async16(Vbase + (size_t)rS * 2048 + s1 + cS, vd + tid * 8);
        async16(Vbase + (size_t)(rS + 32) * 2048 + s1 + cS, vd + 2048 + tid * 8);
      }
      if (it <= diag) {  // wave-uniform; keys beyond diag are fully masked
        const u16* Kc = Ks[it & 1];
        const u16* Vc = Vs[it & 1];
        v8s ak[2][4], av[2][4];
#pragma unroll
        for (int kk = 0; kk < 2; ++kk) {
          const int go = (((kk * 4 + quad) ^ (ln & 7)) << 3);
#pragma unroll
          for (int i = 0; i < 4; ++i) {
            ak[kk][i] = *(const v8s*)(Kc + (i * 16 + ln) * 64 + go);
            av[kk][i] = *(const v8s*)(Vc + (i * 16 + ln) * 64 + go);
          }
        }
        const int s0 = it * 64;
        if (it == diag) {
          qk_sm_pv<true>(ak, av, Pw, aq0, od0, l0, s0, qrow0, ln, quad, swz);
          qk_sm_pv<true>(ak, av, Pw, aq1, od1, l1, s0, qrow1, ln, quad, swz);
        } else {
          qk_sm_pv<false>(ak, av, Pw, aq0, od0, l0, s0, qrow0, ln, quad, swz);
          qk_sm_pv<false>(ak, av, Pw, aq1, od1, l1, s0, qrow1, ln, quad, swz);
        }
      }
    }
    __syncthreads();  // last tile's LDS reads done before next phase restages buf0

    flash_epi(l0, od0, S0 + ln, b, h, quad, O);
    flash_epi(l1, od1, S0 + 16 + ln, b, h, quad, O);
  }
}

extern "C" void kernel_launch(void* const* d_in, const int* in_sizes, int n_in,
                              void* d_out, int out_size, void* d_ws, size_t ws_size,
                              hipStream_t stream) {
  const float* x     = (const float*)d_in[0];
  const float* w_qkv = (const float*)d_in[1];
  const float* w_out = (const float*)d_in[2];
  float* out = (float*)d_out;
  char* ws = (char*)d_ws;
  u16* xb    = (u16*)(ws);              // 16 MB   [0, 16777216)
  u16* wqkvb = (u16*)(ws + 16777216);   // 6 MB    [16777216, 23068672)
  u16* woutb = (u16*)(ws + 23068672);   // 2 MB    [23068672, 25165824)
  u16* qh    = (u16*)(ws + 25165824);   // [64][2048][64]  16 MB
  u16* kh    = (u16*)(ws + 41943040);   // [64][2048][64]  16 MB
  u16* vt    = (u16*)(ws + 58720256);   // [64][64][2048]  16 MB
  u16* oa    = (u16*)(ws + 75497472);   // [8192][1024]    16 MB

  cast_all_k<<<12288, 256, 0, stream>>>(x, w_qkv, w_out, (u16*)ws);
  gemm_qkv_rope<<<dim3(64, 24), 256, 0, stream>>>(xb, wqkvb, qh, kh, vt);
  flash_k<<<dim3(64, 8), 256, 0, stream>>>(qh, kh, vt, oa);
  gemm_out_k<<<dim3(64, 16), 256, 0, stream>>>(oa, woutb, out);
}